// Round 5
// baseline (127.607 us; speedup 1.0000x reference)
//
#include <hip/hip_runtime.h>
#include <math.h>

// GEBLNet via Gram-matrix reduction.
// R22 = R19 inner loops, restructured as 2 POINTS PER WAVE (4096 x 64).
// EVIDENCE (R19-R21, Little's law): point throughput pinned at ~0.44
// points/us/CU (one point per ~5400 CU-cycles) while per-block latency and
// residency trade off exactly (N = X*T). Occupancy is an OUTPUT, not a cap.
// So: cut per-POINT cost. Each lane runs its old job for points A and B in
// the same iteration (same (uu,v,jk)/(q,u) indices):
//   - w1 row loads + CTt loads + all index math amortized across 2 points
//     (per-point VMEM and addressing ~halve),
//   - two independent FMA/LDS chains per lane (ILP x2 on latency paths),
//   - workgroups halve 8192->4096 (hedges CP dispatch-rate floor).
// NOT R20 (two waves per block regressed): this is ONE wave, two chains.
// LESSON (R21): jk-thirds VMEM cut alone was flat -> reverted; keep R19 2a.
// LESSON (R21): shuffle reductions in phases 3/6 kept (fewer barriers).
// LESSON (R20): multi-wave wgs regress. LESSON (R16): merged 2a+2b VGPR 84
// regress-by-merge; R21 showed VGPR 84 itself is tolerable (dur flat).
// LESSON (R15): fine-grained jobs beat wide. LESSON (R11): direct-w2
// contraction regresses. LESSON (R4+R7): launch_bounds min-waves arg ->
// spill. LESSON (R6): never reinterpret-cast local arrays.

#define NPTS 8192
#define THRESH 0.001f

__global__ void geblnet_setup(const float* __restrict__ w2,
                              float4* __restrict__ CTt) {
    int j = blockIdx.x * blockDim.x + threadIdx.x;
    if (j >= 12 * 169) return;
    int u = j / 169, it = j % 169;
    const float* W = w2 + u * 25 * 25 * 2;
#define WR(v, w) W[((v) * 25 + (w)) * 2]
#define WI(v, w) W[((v) * 25 + (w)) * 2 + 1]
    float c0, c1, c2, c3;
    if (it < 78) {                       // S pairs, a<=b
        int q = it, a = 0;
        while (q >= 12 - a) { q -= 12 - a; ++a; }
        int b = a + q;
        float ar = WR(a, b) + (a != b ? WR(b, a) : 0.f);
        float ai = WI(a, b) + (a != b ? WI(b, a) : 0.f);
        float br = WR(12 + a, 12 + b) + (a != b ? WR(12 + b, 12 + a) : 0.f);
        float bi = WI(12 + a, 12 + b) + (a != b ? WI(12 + b, 12 + a) : 0.f);
        c0 = ar + br; c1 = bi - ai; c2 = ai + bi; c3 = ar - br;
    } else if (it < 156) {               // Hm pairs, a<=b
        int q = it - 78, a = 0;
        while (q >= 12 - a) { q -= 12 - a; ++a; }
        int b = a + q;
        if (a != b) {
            float gr = WR(a, 12 + b) + WR(12 + b, a);
            float gi = WI(a, 12 + b) + WI(12 + b, a);
            float dr = WR(b, 12 + a) + WR(12 + a, b);
            float di = WI(b, 12 + a) + WI(12 + a, b);
            c0 = gr + dr; c1 = di - gi; c2 = gi + di; c3 = gr - dr;
        } else {
            float er = WR(a, 12 + a) + WR(12 + a, a);
            float ei = WI(a, 12 + a) + WI(12 + a, a);
            c0 = er; c1 = 0.f; c2 = ei; c3 = 0.f;
        }
    } else if (it < 168) {               // trace terms
        int a = it - 156;
        float fr = WR(a, 24) + WR(24, a), fi = WI(a, 24) + WI(24, a);
        float pr = WR(12 + a, 24) + WR(24, 12 + a);
        float pi = WI(12 + a, 24) + WI(24, 12 + a);
        c0 = fr + pr; c1 = pi - fi; c2 = fi + pi; c3 = fr - pr;
    } else {                             // unit-unit
        c0 = 3.f * WR(24, 24); c1 = 0.f; c2 = 3.f * WI(24, 24); c3 = 0.f;
    }
    CTt[it * 12 + u] = make_float4(c0, c1, c2, c3);
#undef WR
#undef WI
}

// Scratch union: bs dead after phase 2b; phase-3..6 scratch reuses it.
union Scr {
    float2 bs[702];                     // B[uu][v][jk], rows exact 9 (5616 B)
    struct {
        float2 tpar[60];                // phase 5 partials
        float2 tr1[12];                 // layer-1 traces (read in phase 4)
        float  sc1[12];                 // combined gerelu+trnorm scale
    } s;
};

__global__ __launch_bounds__(64) void geblnet_main(
    const float2* __restrict__ x2,      // (8192, 10, 9) complex
    const float2* __restrict__ w1g,     // (12,13,13) complex
    const float* __restrict__ dw,       // (24,)
    const float* __restrict__ db,       // (1,)
    const float4* __restrict__ CTt,     // (169,12)
    float* __restrict__ out)            // (8192,)
{
    // Per-point LDS banks; overlay: phases 1-2 = We row-major (stride 10);
    //          phases 4-5 = GV[169].
    __shared__ float2 WeGV_[2][170];    // 2720 B
    __shared__ Scr S_[2];               // 11232 B
    __shared__ float2 Hs_[2][108];      // 1728 B
    // total 15680 B -> 16384 alloc

    const int t = threadIdx.x;
    const int pA = blockIdx.x * 2;
    const int pB = pA + 1;

    float2* WeA = WeGV_[0];
    float2* WeB = WeGV_[1];
    float2* HsA = Hs_[0];
    float2* HsB = Hs_[1];

    // ---- phase 1: build We channels 0..12 for both points
    for (int j = t; j < 117; j += 64) {
        int v = j / 9, ik = j - v * 9;
        int i = ik / 3, jj = ik - i * 3;
        float2 vaA, vaB;
        if (v < 6) {
            vaA = x2[(size_t)pA * 90 + (4 + v) * 9 + ik];
            vaB = x2[(size_t)pB * 90 + (4 + v) * 9 + ik];
        } else if (v < 12) {
            float2 sA = x2[(size_t)pA * 90 + (v - 2) * 9 + jj * 3 + i];
            float2 sB = x2[(size_t)pB * 90 + (v - 2) * 9 + jj * 3 + i];
            vaA = make_float2(sA.x, -sA.y);
            vaB = make_float2(sB.x, -sB.y);
        } else {
            vaA = make_float2((i == jj) ? 1.f : 0.f, 0.f);
            vaB = vaA;
        }
        WeA[v * 10 + ik] = vaA;
        WeB[v * 10 + ik] = vaB;
    }
    __syncthreads();

    // ---- phase 2: layer 1, two u-half passes, both points per job
    #pragma unroll 1
    for (int g = 0; g < 2; ++g) {
        const int u0 = g * 6;
        // 2a: B[uu][v][jk] = sum_w w1[u0+uu,v,w] * We[w][jk]
        //     cc row loaded ONCE, serves both points. We reads: per-w
        //     broadcast (addr depends only on jk): no bank conflicts.
        {
            int uu = 0, rem = t;
            #pragma unroll 1
            for (int e = t; e < 702; e += 64) {
                int v = rem / 9, jk = rem - v * 9;
                const float2* cp = w1g + ((u0 + uu) * 13 + v) * 13; // contig
                float brA = 0.f, biA = 0.f, brB = 0.f, biB = 0.f;
                #pragma unroll
                for (int w = 0; w < 13; ++w) {
                    float2 cc = cp[w];
                    float2 eA = WeA[w * 10 + jk];
                    float2 eB = WeB[w * 10 + jk];
                    brA += cc.x * eA.x - cc.y * eA.y;
                    biA += cc.x * eA.y + cc.y * eA.x;
                    brB += cc.x * eB.x - cc.y * eB.y;
                    biB += cc.x * eB.y + cc.y * eB.x;
                }
                S_[0].bs[(uu * 13 + v) * 9 + jk] = make_float2(brA, biA);
                S_[1].bs[(uu * 13 + v) * 9 + jk] = make_float2(brB, biB);
                rem += 64;
                if (rem >= 117) { rem -= 117; ++uu; }
            }
        }
        __syncthreads();
        // 2b: H[u0+uu][i][k] = sum_{v,j} We[v][i][j] * B[uu][v][j*3+k]
        if (t < 54) {
            int uu = t / 9, ik = t - uu * 9;
            int i = ik / 3, k = ik - i * 3;
            float hrA = 0.f, hiA = 0.f, hrB = 0.f, hiB = 0.f;
            #pragma unroll
            for (int v = 0; v < 13; ++v) {
                const float2* aA = &WeA[v * 10 + i * 3];
                const float2* aB = &WeB[v * 10 + i * 3];
                const float2* bA = &S_[0].bs[(uu * 13 + v) * 9 + k];
                const float2* bB = &S_[1].bs[(uu * 13 + v) * 9 + k];
                #pragma unroll
                for (int j = 0; j < 3; ++j) {
                    float2 ajA = aA[j], bjA = bA[j * 3];
                    float2 ajB = aB[j], bjB = bB[j * 3];
                    hrA += ajA.x * bjA.x - ajA.y * bjA.y;
                    hiA += ajA.x * bjA.y + ajA.y * bjA.x;
                    hrB += ajB.x * bjB.x - ajB.y * bjB.y;
                    hiB += ajB.x * bjB.y + ajB.y * bjB.x;
                }
            }
            HsA[(u0 + uu) * 9 + ik] = make_float2(hrA, hiA);
            HsB[(u0 + uu) * 9 + ik] = make_float2(hrB, hiB);
        }
        __syncthreads();
    }

    // ---- phase 3: traces + gerelu + trnorm scales
    //      lanes 0-15: point A (u = t), lanes 16-31: point B (u = t-16)
    {
        const int grp = t >> 4, lu = t & 15;
        float2 tt = make_float2(0.f, 0.f);
        float gg = 0.f, tra_v = 0.f;
        if (grp < 2 && lu < 12) {
            const float2* H = (grp == 0) ? HsA : HsB;
            float2 a = H[lu * 9 + 0], b = H[lu * 9 + 4], c = H[lu * 9 + 8];
            tt = make_float2(a.x + b.x + c.x, a.y + b.y + c.y);
            gg = tt.x > 0.f ? tt.x : 0.f;
            tra_v = gg * sqrtf(tt.x * tt.x + tt.y * tt.y);
        }
        float m = tra_v;                 // inactive lanes contribute 0
        m += __shfl_xor(m, 1, 16);
        m += __shfl_xor(m, 2, 16);
        m += __shfl_xor(m, 4, 16);
        m += __shfl_xor(m, 8, 16);
        if (grp < 2 && lu < 12) {
            S_[grp].s.tr1[lu] = tt;
            S_[grp].s.sc1[lu] = gg / fmaxf(m * (1.f / 12.f), THRESH);
        }
    }
    __syncthreads();

    // ---- phase 4: Gram values -> GV for both points (index math shared)
    for (int it = t; it < 169; it += 64) {
        float2 vA, vB;
        if (it < 156) {
            int q = it < 78 ? it : it - 78;
            float fs = sqrtf(625.0f - 8.0f * (float)q);   // exact at edges
            int a = (int)((25.0f - fs) * 0.5f);
            int b = q - (a * (25 - a)) / 2 + a;
            const float2* HaA = &HsA[a * 9];
            const float2* HbA = &HsA[b * 9];
            const float2* HaB = &HsB[a * 9];
            const float2* HbB = &HsB[b * 9];
            float sA = S_[0].s.sc1[a] * S_[0].s.sc1[b];
            float sB = S_[1].s.sc1[a] * S_[1].s.sc1[b];
            float vrA = 0.f, viA = 0.f, vrB = 0.f, viB = 0.f;
            if (it < 78) {                    // S = tr(Aa Ab)
                #pragma unroll
                for (int i = 0; i < 3; ++i)
                    #pragma unroll
                    for (int jj = 0; jj < 3; ++jj) {
                        float2 A = HaA[i * 3 + jj], B = HbA[jj * 3 + i];
                        vrA += A.x * B.x - A.y * B.y;
                        viA += A.x * B.y + A.y * B.x;
                        float2 C = HaB[i * 3 + jj], D = HbB[jj * 3 + i];
                        vrB += C.x * D.x - C.y * D.y;
                        viB += C.x * D.y + C.y * D.x;
                    }
            } else {                          // Hm = tr(Aa Ab^H)
                #pragma unroll
                for (int e = 0; e < 9; ++e) {
                    float2 A = HaA[e], B = HbA[e];
                    vrA += A.x * B.x + A.y * B.y;
                    viA += A.y * B.x - A.x * B.y;
                    float2 C = HaB[e], D = HbB[e];
                    vrB += C.x * D.x + C.y * D.y;
                    viB += C.y * D.x - C.x * D.y;
                }
            }
            vA = make_float2(sA * vrA, sA * viA);
            vB = make_float2(sB * vrB, sB * viB);
        } else if (it < 168) {
            int a = it - 156;
            float sA = S_[0].s.sc1[a]; float2 tA = S_[0].s.tr1[a];
            float sB = S_[1].s.sc1[a]; float2 tB = S_[1].s.tr1[a];
            vA = make_float2(sA * tA.x, sA * tA.y);
            vB = make_float2(sB * tB.x, sB * tB.y);
        } else {
            vA = make_float2(1.f, 0.f);
            vB = vA;
        }
        WeA[it] = vA;
        WeB[it] = vB;
    }
    __syncthreads();

    // ---- phase 5: coefficient contraction, lane=(q,u), 60 active
    //      CTt load shared across both points.
    if (t < 60) {
        int q = t / 12, u = t - q * 12;
        int i0 = q * 34, i1 = (q == 4) ? 169 : i0 + 34;
        float treA = 0.f, timA = 0.f, treB = 0.f, timB = 0.f;
        #pragma unroll 4
        for (int it = i0; it < i1; ++it) {
            float4 c = CTt[it * 12 + u];
            float2 gA = WeA[it];
            float2 gB = WeB[it];
            treA += c.x * gA.x + c.y * gA.y;
            timA += c.z * gA.x + c.w * gA.y;
            treB += c.x * gB.x + c.y * gB.y;
            timB += c.z * gB.x + c.w * gB.y;
        }
        S_[0].s.tpar[u * 5 + q] = make_float2(treA, timA);
        S_[1].s.tpar[u * 5 + q] = make_float2(treB, timB);
    }
    __syncthreads();

    // ---- phase 6: layer-2 gerelu + trnorm + dense head
    //      lanes 0-15: point A, lanes 16-31: point B; shuffle reduce.
    {
        const int grp = t >> 4, lu = t & 15;
        float2 tt = make_float2(0.f, 0.f);
        float gg = 0.f, tra_v = 0.f;
        if (grp < 2 && lu < 12) {
            const Scr* Sp = &S_[grp];
            #pragma unroll
            for (int q = 0; q < 5; ++q) {
                float2 A = Sp->s.tpar[lu * 5 + q];
                tt.x += A.x; tt.y += A.y;
            }
            gg = tt.x > 0.f ? tt.x : 0.f;
            tra_v = gg * sqrtf(tt.x * tt.x + tt.y * tt.y);
        }
        float m = tra_v;
        m += __shfl_xor(m, 1, 16);
        m += __shfl_xor(m, 2, 16);
        m += __shfl_xor(m, 4, 16);
        m += __shfl_xor(m, 8, 16);
        float term = 0.f;
        if (grp < 2 && lu < 12) {
            float inv = 1.f / fmaxf(m * (1.f / 12.f), THRESH);
            float s = gg * inv * (1.f / 3.f);
            term = s * (tt.x * dw[2 * lu] + tt.y * dw[2 * lu + 1]);
        }
        term += __shfl_xor(term, 1, 16);
        term += __shfl_xor(term, 2, 16);
        term += __shfl_xor(term, 4, 16);
        term += __shfl_xor(term, 8, 16);
        if (grp < 2 && lu == 0) out[pA + grp] = term + db[0];
    }
}

extern "C" void kernel_launch(void* const* d_in, const int* in_sizes, int n_in,
                              void* d_out, int out_size, void* d_ws, size_t ws_size,
                              hipStream_t stream) {
    const float* x  = (const float*)d_in[0];
    const float* w1 = (const float*)d_in[1];
    const float* w2 = (const float*)d_in[2];
    const float* dw = (const float*)d_in[3];
    const float* db = (const float*)d_in[4];
    float* outp = (float*)d_out;
    float4* CTt = (float4*)d_ws;          // 12*169*16 B = 32448 B

    geblnet_setup<<<(12 * 169 + 255) / 256, 256, 0, stream>>>(w2, CTt);

    geblnet_main<<<NPTS / 2, 64, 0, stream>>>(
        (const float2*)x, (const float2*)w1, dw, db, CTt, outp);
}